// Round 2
// baseline (487.302 us; speedup 1.0000x reference)
//
#include <hip/hip_runtime.h>
#include <hip/hip_bf16.h>
#include <stdint.h>

#define N_NODES   16384
#define DIMM      256
#define HEADS     8
#define HDIM      32
#define NUM_GLOBAL 4
#define N_TOT     (N_NODES + NUM_GLOBAL)   // 16388
#define E_LOCAL   131072
#define E_EXP     65536
#define E_CSR     (E_LOCAL + E_EXP)        // 196608

typedef __hip_bfloat16 bf16;

__device__ __forceinline__ float b2f(bf16 v) { return __bfloat162float(v); }

// Dual-dtype load: isb=1 -> buffer is bf16-packed, else fp32.
__device__ __forceinline__ float loadF(const void* __restrict__ p, int i, int isb) {
    if (isb) return b2f(((const bf16*)p)[i]);
    return ((const float*)p)[i];
}

// ---------------------------------------------------------------------------
// Dtype probe: for a bf16-packed buffer of ~N(0,1) data, bits [14:7] of each
// 32-bit word are the even element's exponent field -> concentrated near 0x7E.
// For an fp32 buffer those bits are low-mantissa bits -> uniform over 0..255.
// Count in-range hits over 64 words; >=48 -> bf16.
// ---------------------------------------------------------------------------
__global__ void probe_dtype(const void* __restrict__ x, int* __restrict__ flag) {
    const uint32_t* w = (const uint32_t*)x;
    int lane = threadIdx.x;            // 64 threads
    uint32_t word = w[lane];
    int ex = (word >> 7) & 0xFF;
    int ok = (ex >= 0x60 && ex <= 0x8F) ? 1 : 0;
    unsigned long long m = __ballot(ok);
    if (lane == 0) flag[0] = (__popcll(m) >= 48) ? 1 : 0;
}

// ---------------------------------------------------------------------------
// QKV projection: X_full(16388x256) @ Wqkv(256x768) + b -> Q,K,V fp32
// Tiles: BM=64, BN=64, BK=32. 256 threads, 4x4 micro-tile each.
// ---------------------------------------------------------------------------
__global__ __launch_bounds__(256) void qkv_gemm(
    const void* __restrict__ x, const void* __restrict__ gtok,
    const void* __restrict__ Wqkv, const void* __restrict__ bqkv,
    const int* __restrict__ flag,
    float* __restrict__ Q, float* __restrict__ K, float* __restrict__ V)
{
    const int isb = flag[0];
    __shared__ float Xs[64][33];
    __shared__ float Ws[32][65];
    const int n0 = blockIdx.x * 64;          // cols of 768
    const int m0 = blockIdx.y * 64;          // rows of 16388
    const int t  = threadIdx.x;
    const int tx = t & 15, ty = t >> 4;

    float acc[4][4] = {};

    for (int k0 = 0; k0 < DIMM; k0 += 32) {
        #pragma unroll
        for (int i = 0; i < 8; ++i) {
            int lin = t + 256 * i;
            int r = lin >> 5, c = lin & 31;
            int row = m0 + r;
            float val = 0.f;
            if (row < N_NODES)      val = loadF(x, row * DIMM + k0 + c, isb);
            else if (row < N_TOT)   val = loadF(gtok, (row - N_NODES) * DIMM + k0 + c, isb);
            Xs[r][c] = val;
        }
        #pragma unroll
        for (int i = 0; i < 8; ++i) {
            int lin = t + 256 * i;
            int r = lin >> 6, c = lin & 63;
            Ws[r][c] = loadF(Wqkv, (k0 + r) * 768 + n0 + c, isb);
        }
        __syncthreads();
        #pragma unroll
        for (int kk = 0; kk < 32; ++kk) {
            float a[4], b[4];
            #pragma unroll
            for (int i = 0; i < 4; ++i) a[i] = Xs[ty * 4 + i][kk];
            #pragma unroll
            for (int j = 0; j < 4; ++j) b[j] = Ws[kk][tx * 4 + j];
            #pragma unroll
            for (int i = 0; i < 4; ++i)
                #pragma unroll
                for (int j = 0; j < 4; ++j)
                    acc[i][j] += a[i] * b[j];
        }
        __syncthreads();
    }

    #pragma unroll
    for (int i = 0; i < 4; ++i) {
        int row = m0 + ty * 4 + i;
        if (row >= N_TOT) continue;
        #pragma unroll
        for (int j = 0; j < 4; ++j) {
            int col = n0 + tx * 4 + j;       // 0..767
            float val = acc[i][j] + loadF(bqkv, col, isb);
            int s = col >> 8;                // 0=Q 1=K 2=V
            int c = col & 255;
            float* dst = (s == 0) ? Q : (s == 1) ? K : V;
            dst[row * DIMM + c] = val;
        }
    }
}

// ---------------------------------------------------------------------------
// CSR build for (local + expander) edges keyed by dst. n2g edges skipped:
// global-token outputs are discarded by the reference (out[:N]).
// ---------------------------------------------------------------------------
__global__ void count_edges(const int* __restrict__ ei, const int* __restrict__ xei,
                            int* __restrict__ cnt)
{
    int e = blockIdx.x * blockDim.x + threadIdx.x;
    if (e < E_LOCAL) {
        atomicAdd(&cnt[ei[E_LOCAL + e]], 1);
    } else if (e < E_CSR) {
        int ee = e - E_LOCAL;
        atomicAdd(&cnt[xei[E_EXP + ee]], 1);
    }
}

__global__ void scan_kernel(int* __restrict__ cnt_cursor, int* __restrict__ rowstart)
{
    __shared__ int sdata[256];
    const int t = threadIdx.x;
    int carry = 0;
    for (int c0 = 0; c0 < N_NODES; c0 += 256) {
        int v = cnt_cursor[c0 + t];
        sdata[t] = v;
        __syncthreads();
        for (int off = 1; off < 256; off <<= 1) {
            int tmp = (t >= off) ? sdata[t - off] : 0;
            __syncthreads();
            sdata[t] += tmp;
            __syncthreads();
        }
        int excl = carry + sdata[t] - v;
        rowstart[c0 + t]   = excl;
        cnt_cursor[c0 + t] = excl;
        carry += sdata[255];
        __syncthreads();
    }
    if (t == 0) rowstart[N_NODES] = carry;
}

__global__ void fill_edges(const int* __restrict__ ei, const int* __restrict__ xei,
                           int* __restrict__ cursor, int* __restrict__ adj)
{
    int e = blockIdx.x * blockDim.x + threadIdx.x;
    int s, d;
    if (e < E_LOCAL)      { s = ei[e];            d = ei[E_LOCAL + e]; }
    else if (e < E_CSR)   { int ee = e - E_LOCAL; s = xei[ee]; d = xei[E_EXP + ee]; }
    else return;
    int pos = atomicAdd(&cursor[d], 1);
    adj[pos] = s;
}

// ---------------------------------------------------------------------------
// Gather attention: one wave per dst node. Lane l owns cols 4l..4l+3; lanes
// 8h..8h+7 cover head h. Per edge: partial dot, 3x shfl_xor reduce within the
// 8-lane head group, exp, weighted V accumulate. No max-subtraction needed
// (scores O(1..10), exp safe in fp32; identical math to reference softmax).
// O is written IN-PLACE over Q (each wave reads only its own Q row, then
// writes O to that same row; no cross-wave Q reads -> aliasing is safe).
// ---------------------------------------------------------------------------
__global__ __launch_bounds__(256) void attn_kernel(
    float* __restrict__ QO, const float* __restrict__ K,
    const float* __restrict__ V, const int* __restrict__ rowstart,
    const int* __restrict__ adj)
{
    const int wave = (blockIdx.x * blockDim.x + threadIdx.x) >> 6;
    const int lane = threadIdx.x & 63;
    if (wave >= N_NODES) return;
    const int n = wave;
    const float scale = 0.1767766952966369f;  // 32^-0.5

    float4 q = ((const float4*)(QO + (size_t)n * DIMM))[lane];
    q.x *= scale; q.y *= scale; q.z *= scale; q.w *= scale;

    float4 acc = make_float4(0.f, 0.f, 0.f, 0.f);
    float dsum = 0.f;

    const int rs = rowstart[n];
    const int re = rowstart[n + 1];
    const int ne = (re - rs) + 5;            // self + 4 globals + CSR list

    for (int j = 0; j < ne; ++j) {
        int s;
        if (j == 0)       s = n;
        else if (j <= 4)  s = N_NODES + (j - 1);
        else              s = adj[rs + j - 5];

        float4 k = ((const float4*)(K + (size_t)s * DIMM))[lane];
        float p = q.x * k.x + q.y * k.y + q.z * k.z + q.w * k.w;
        p += __shfl_xor(p, 1);
        p += __shfl_xor(p, 2);
        p += __shfl_xor(p, 4);               // p = head score in all 8 lanes
        float w = __expf(p);
        dsum += w;
        float4 v = ((const float4*)(V + (size_t)s * DIMM))[lane];
        acc.x += w * v.x; acc.y += w * v.y; acc.z += w * v.z; acc.w += w * v.w;
    }

    float r = 1.0f / dsum;
    acc.x *= r; acc.y *= r; acc.z *= r; acc.w *= r;
    ((float4*)(QO + (size_t)n * DIMM))[lane] = acc;
}

// ---------------------------------------------------------------------------
// Output projection: O(16384x256 fp32) @ Wout(256x256) + bout -> out
// ---------------------------------------------------------------------------
__global__ __launch_bounds__(256) void out_gemm(
    const float* __restrict__ O, const void* __restrict__ Wout,
    const void* __restrict__ bout, const int* __restrict__ flag,
    void* __restrict__ out)
{
    const int isb = flag[0];
    __shared__ float Xs[64][33];
    __shared__ float Ws[32][65];
    const int n0 = blockIdx.x * 64;
    const int m0 = blockIdx.y * 64;
    const int t  = threadIdx.x;
    const int tx = t & 15, ty = t >> 4;

    float acc[4][4] = {};

    for (int k0 = 0; k0 < DIMM; k0 += 32) {
        #pragma unroll
        for (int i = 0; i < 8; ++i) {
            int lin = t + 256 * i;
            int r = lin >> 5, c = lin & 31;
            Xs[r][c] = O[(size_t)(m0 + r) * DIMM + k0 + c];
        }
        #pragma unroll
        for (int i = 0; i < 8; ++i) {
            int lin = t + 256 * i;
            int r = lin >> 6, c = lin & 63;
            Ws[r][c] = loadF(Wout, (k0 + r) * DIMM + n0 + c, isb);
        }
        __syncthreads();
        #pragma unroll
        for (int kk = 0; kk < 32; ++kk) {
            float a[4], b[4];
            #pragma unroll
            for (int i = 0; i < 4; ++i) a[i] = Xs[ty * 4 + i][kk];
            #pragma unroll
            for (int j = 0; j < 4; ++j) b[j] = Ws[kk][tx * 4 + j];
            #pragma unroll
            for (int i = 0; i < 4; ++i)
                #pragma unroll
                for (int j = 0; j < 4; ++j)
                    acc[i][j] += a[i] * b[j];
        }
        __syncthreads();
    }

    #pragma unroll
    for (int i = 0; i < 4; ++i) {
        int row = m0 + ty * 4 + i;
        #pragma unroll
        for (int j = 0; j < 4; ++j) {
            int col = n0 + tx * 4 + j;
            float val = acc[i][j] + loadF(bout, col, isb);
            size_t idx = (size_t)row * DIMM + col;
            if (isb) ((bf16*)out)[idx] = __float2bfloat16(val);
            else     ((float*)out)[idx] = val;
        }
    }
}

// ---------------------------------------------------------------------------
extern "C" void kernel_launch(void* const* d_in, const int* in_sizes, int n_in,
                              void* d_out, int out_size, void* d_ws, size_t ws_size,
                              hipStream_t stream)
{
    const void* x    = d_in[0];
    const int*  ei   = (const int*)d_in[1];
    const int*  xei  = (const int*)d_in[2];
    const void* Wqkv = d_in[3];
    const void* bqkv = d_in[4];
    const void* Wout = d_in[5];
    const void* bout = d_in[6];
    const void* gtok = d_in[7];

    // workspace layout: ints first, then fp32 arrays (~51.3 MB total)
    int* flag     = (int*)d_ws;
    int* rowstart = flag + 1;                 // N_NODES+1
    int* cursor   = rowstart + (N_NODES + 1); // N_NODES
    int* adj      = cursor + N_NODES;         // E_CSR
    float* fbase  = (float*)(adj + E_CSR);
    // pad to 16B alignment for float4 access
    uintptr_t fb = ((uintptr_t)fbase + 15) & ~(uintptr_t)15;
    float* K  = (float*)fb;
    float* V  = K + (size_t)N_TOT * DIMM;
    float* QO = V + (size_t)N_TOT * DIMM;     // Q, overwritten in-place by O

    hipMemsetAsync(cursor, 0, N_NODES * sizeof(int), stream);

    probe_dtype<<<1, 64, 0, stream>>>(x, flag);
    qkv_gemm<<<dim3(12, 257), 256, 0, stream>>>(x, gtok, Wqkv, bqkv, flag, QO, K, V);
    count_edges<<<(E_CSR + 255) / 256, 256, 0, stream>>>(ei, xei, cursor);
    scan_kernel<<<1, 256, 0, stream>>>(cursor, rowstart);
    fill_edges<<<(E_CSR + 255) / 256, 256, 0, stream>>>(ei, xei, cursor, adj);
    attn_kernel<<<N_NODES / 4, 256, 0, stream>>>(QO, K, V, rowstart, adj);
    out_gemm<<<dim3(4, 256), 256, 0, stream>>>(QO, Wout, bout, flag, d_out);
}

// Round 7
// 355.312 us; speedup vs baseline: 1.3715x; 1.3715x over previous
//
#include <hip/hip_runtime.h>
#include <hip/hip_bf16.h>
#include <stdint.h>

#define N_NODES   16384
#define DIMM      256
#define HEADS     8
#define HDIM      32
#define NUM_GLOBAL 4
#define N_TOT     (N_NODES + NUM_GLOBAL)   // 16388
#define E_LOCAL   131072
#define E_EXP     65536
#define E_CSR     (E_LOCAL + E_EXP)        // 196608

// ---------------------------------------------------------------------------
// QKV projection (fp32): X_full(16388x256) @ Wqkv(256x768) + b -> Q,K,V fp32.
// R2-proven tile structure (BM=64,BN=64,BK=32, 4x4 micro), float4 staging.
// ---------------------------------------------------------------------------
__global__ __launch_bounds__(256) void qkv_gemm(
    const float* __restrict__ x, const float* __restrict__ gtok,
    const float* __restrict__ W, const float* __restrict__ bias,
    float* __restrict__ Q, float* __restrict__ K, float* __restrict__ V)
{
    __shared__ float Xs[64][33];
    __shared__ float Ws[32][65];
    const int n0 = blockIdx.x * 64;          // cols of 768
    const int m0 = blockIdx.y * 64;          // rows of 16388 (257 blocks)
    const int t  = threadIdx.x;
    const int tx = t & 15, ty = t >> 4;

    float acc[4][4] = {};

    for (int k0 = 0; k0 < DIMM; k0 += 32) {
        // X tile 64x32 = 512 float4; thread t stages chunks t and t+256
        #pragma unroll
        for (int i = 0; i < 2; ++i) {
            int c4 = t + 256 * i;
            int r = c4 >> 3, cc = (c4 & 7) * 4;
            int row = m0 + r;
            float4 v = make_float4(0.f, 0.f, 0.f, 0.f);
            if (row < N_NODES)
                v = *(const float4*)(x + (size_t)row * DIMM + k0 + cc);
            else if (row < N_TOT)
                v = *(const float4*)(gtok + (size_t)(row - N_NODES) * DIMM + k0 + cc);
            Xs[r][cc] = v.x; Xs[r][cc + 1] = v.y; Xs[r][cc + 2] = v.z; Xs[r][cc + 3] = v.w;
        }
        // W tile 32x64 = 512 float4
        #pragma unroll
        for (int i = 0; i < 2; ++i) {
            int c4 = t + 256 * i;
            int r = c4 >> 4, cc = (c4 & 15) * 4;
            float4 v = *(const float4*)(W + (size_t)(k0 + r) * 768 + n0 + cc);
            Ws[r][cc] = v.x; Ws[r][cc + 1] = v.y; Ws[r][cc + 2] = v.z; Ws[r][cc + 3] = v.w;
        }
        __syncthreads();
        #pragma unroll
        for (int kk = 0; kk < 32; ++kk) {
            float a[4], b[4];
            #pragma unroll
            for (int i = 0; i < 4; ++i) a[i] = Xs[ty * 4 + i][kk];
            #pragma unroll
            for (int j = 0; j < 4; ++j) b[j] = Ws[kk][tx * 4 + j];
            #pragma unroll
            for (int i = 0; i < 4; ++i)
                #pragma unroll
                for (int j = 0; j < 4; ++j)
                    acc[i][j] += a[i] * b[j];
        }
        __syncthreads();
    }

    #pragma unroll
    for (int i = 0; i < 4; ++i) {
        int row = m0 + ty * 4 + i;
        if (row >= N_TOT) continue;
        #pragma unroll
        for (int j = 0; j < 4; ++j) {
            int col = n0 + tx * 4 + j;       // 0..767
            float val = acc[i][j] + bias[col];
            int s = col >> 8;                // 0=Q 1=K 2=V
            int c = col & 255;
            float* dst = (s == 0) ? Q : (s == 1) ? K : V;
            dst[(size_t)row * DIMM + c] = val;
        }
    }
}

// ---------------------------------------------------------------------------
// Output projection (fp32): O(16384x256 fp32, in QO) @ Wout(256x256) + bout
// -> out fp32.
// ---------------------------------------------------------------------------
__global__ __launch_bounds__(256) void out_gemm(
    const float* __restrict__ O, const float* __restrict__ W,
    const float* __restrict__ bias, float* __restrict__ out)
{
    __shared__ float Xs[64][33];
    __shared__ float Ws[32][65];
    const int n0 = blockIdx.x * 64;          // 0..192
    const int m0 = blockIdx.y * 64;          // 0..16320
    const int t  = threadIdx.x;
    const int tx = t & 15, ty = t >> 4;

    float acc[4][4] = {};

    for (int k0 = 0; k0 < DIMM; k0 += 32) {
        #pragma unroll
        for (int i = 0; i < 2; ++i) {
            int c4 = t + 256 * i;
            int r = c4 >> 3, cc = (c4 & 7) * 4;
            float4 v = *(const float4*)(O + (size_t)(m0 + r) * DIMM + k0 + cc);
            Xs[r][cc] = v.x; Xs[r][cc + 1] = v.y; Xs[r][cc + 2] = v.z; Xs[r][cc + 3] = v.w;
        }
        #pragma unroll
        for (int i = 0; i < 2; ++i) {
            int c4 = t + 256 * i;
            int r = c4 >> 4, cc = (c4 & 15) * 4;
            float4 v = *(const float4*)(W + (size_t)(k0 + r) * DIMM + n0 + cc);
            Ws[r][cc] = v.x; Ws[r][cc + 1] = v.y; Ws[r][cc + 2] = v.z; Ws[r][cc + 3] = v.w;
        }
        __syncthreads();
        #pragma unroll
        for (int kk = 0; kk < 32; ++kk) {
            float a[4], b[4];
            #pragma unroll
            for (int i = 0; i < 4; ++i) a[i] = Xs[ty * 4 + i][kk];
            #pragma unroll
            for (int j = 0; j < 4; ++j) b[j] = Ws[kk][tx * 4 + j];
            #pragma unroll
            for (int i = 0; i < 4; ++i)
                #pragma unroll
                for (int j = 0; j < 4; ++j)
                    acc[i][j] += a[i] * b[j];
        }
        __syncthreads();
    }

    #pragma unroll
    for (int i = 0; i < 4; ++i) {
        int row = m0 + ty * 4 + i;
        #pragma unroll
        for (int j = 0; j < 4; ++j) {
            int col = n0 + tx * 4 + j;
            float val = acc[i][j] + bias[col];
            val = fminf(fmaxf(val, -1e4f), 1e4f);  // tripwire (no-op valid)
            out[(size_t)row * DIMM + col] = val;
        }
    }
}

// ---------------------------------------------------------------------------
// CSR build (dst-keyed) for local+expander edges. n2g edges skipped (their
// outputs are discarded by the reference's out[:N]).
// ---------------------------------------------------------------------------
__global__ void count_edges(const int* __restrict__ ei, const int* __restrict__ xei,
                            int* __restrict__ cnt)
{
    int e = blockIdx.x * blockDim.x + threadIdx.x;
    if (e < E_LOCAL) {
        atomicAdd(&cnt[ei[E_LOCAL + e]], 1);
    } else if (e < E_CSR) {
        int ee = e - E_LOCAL;
        atomicAdd(&cnt[xei[E_EXP + ee]], 1);
    }
}

// 256 threads; thread t serially scans counts [t*64, t*64+64), block-scan of
// the 256 partials, then writes rowstart and resets cursor to row start.
__global__ void scan_kernel(int* __restrict__ cnt_cursor, int* __restrict__ rowstart)
{
    __shared__ int part[256];
    const int t = threadIdx.x;
    const int base = t * 64;
    int s = 0;
    for (int i = 0; i < 64; ++i) s += cnt_cursor[base + i];
    part[t] = s;
    __syncthreads();
    for (int off = 1; off < 256; off <<= 1) {
        int v = (t >= off) ? part[t - off] : 0;
        __syncthreads();
        part[t] += v;
        __syncthreads();
    }
    int excl = part[t] - s;
    for (int i = 0; i < 64; ++i) {
        int v = cnt_cursor[base + i];
        rowstart[base + i]   = excl;
        cnt_cursor[base + i] = excl;
        excl += v;
    }
    if (t == 255) rowstart[N_NODES] = excl;
}

__global__ void fill_edges(const int* __restrict__ ei, const int* __restrict__ xei,
                           int* __restrict__ cursor, int* __restrict__ adj)
{
    int e = blockIdx.x * blockDim.x + threadIdx.x;
    int s, d;
    if (e < E_LOCAL)      { s = ei[e];            d = ei[E_LOCAL + e]; }
    else if (e < E_CSR)   { int ee = e - E_LOCAL; s = xei[ee]; d = xei[E_EXP + ee]; }
    else return;
    int pos = atomicAdd(&cursor[d], 1);
    adj[pos] = s;
}

// ---------------------------------------------------------------------------
// Gather attention (fp32): one wave per dst node. Lane l owns cols 4l..4l+3;
// lanes 8h..8h+7 cover head h. Per edge: partial dot, 3x shfl_xor within the
// 8-lane head group, exp, weighted V accumulate. Hardening clamps are no-ops
// on valid data. O (fp32) written in-place over this node's own Q row --
// race-free (each wave reads only its own Q row). Exactly R2's passing scheme.
// ---------------------------------------------------------------------------
__global__ __launch_bounds__(256) void attn_kernel(
    float* __restrict__ QO, const float* __restrict__ K,
    const float* __restrict__ V, const int* __restrict__ rowstart,
    const int* __restrict__ adj)
{
    const int wave = (blockIdx.x * blockDim.x + threadIdx.x) >> 6;
    const int lane = threadIdx.x & 63;
    if (wave >= N_NODES) return;
    const int n = wave;
    const float scale = 0.1767766952966369f;  // 32^-0.5

    float4 q = ((const float4*)(QO + (size_t)n * DIMM))[lane];
    q.x *= scale; q.y *= scale; q.z *= scale; q.w *= scale;

    float4 acc = make_float4(0.f, 0.f, 0.f, 0.f);
    float dsum = 0.f;

    const int rs = rowstart[n];
    const int re = rowstart[n + 1];
    const int ne = (re - rs) + 5;            // self + 4 globals + CSR list

    for (int j = 0; j < ne; ++j) {
        int s;
        if (j == 0)       s = n;
        else if (j <= 4)  s = N_NODES + (j - 1);
        else              s = adj[rs + j - 5];
        s = min(max(s, 0), N_TOT - 1);       // tripwire

        float4 k = ((const float4*)(K + (size_t)s * DIMM))[lane];
        float p = q.x * k.x + q.y * k.y + q.z * k.z + q.w * k.w;
        p += __shfl_xor(p, 1);
        p += __shfl_xor(p, 2);
        p += __shfl_xor(p, 4);               // p = head score in all 8 lanes
        p = fminf(p, 80.f);                  // tripwire (scrubs NaN too)
        float w = __expf(p);
        dsum += w;
        float4 v = ((const float4*)(V + (size_t)s * DIMM))[lane];
        acc.x += w * v.x; acc.y += w * v.y; acc.z += w * v.z; acc.w += w * v.w;
    }

    float r = 1.0f / fmaxf(dsum, 1e-30f);    // tripwire
    acc.x = fminf(fmaxf(acc.x * r, -500.f), 500.f);
    acc.y = fminf(fmaxf(acc.y * r, -500.f), 500.f);
    acc.z = fminf(fmaxf(acc.z * r, -500.f), 500.f);
    acc.w = fminf(fmaxf(acc.w * r, -500.f), 500.f);
    ((float4*)(QO + (size_t)n * DIMM))[lane] = acc;
}

// ---------------------------------------------------------------------------
extern "C" void kernel_launch(void* const* d_in, const int* in_sizes, int n_in,
                              void* d_out, int out_size, void* d_ws, size_t ws_size,
                              hipStream_t stream)
{
    const float* x    = (const float*)d_in[0];
    const int*   ei   = (const int*)d_in[1];
    const int*   xei  = (const int*)d_in[2];
    const float* Wqkv = (const float*)d_in[3];
    const float* bqkv = (const float*)d_in[4];
    const float* Wout = (const float*)d_in[5];
    const float* bout = (const float*)d_in[6];
    const float* gtok = (const float*)d_in[7];

    // workspace layout (~51.2 MB; proven fits in R2):
    int* rowstart = (int*)d_ws;               // N_NODES+1
    int* cursor   = rowstart + (N_NODES + 1); // N_NODES
    int* adj      = cursor + N_NODES;         // E_CSR
    const size_t int_bytes = (size_t)(N_NODES + 1 + N_NODES + E_CSR) * sizeof(int);
    uintptr_t fb = ((uintptr_t)(adj + E_CSR) + 15) & ~(uintptr_t)15;
    float* K  = (float*)fb;
    float* V  = K + (size_t)N_TOT * DIMM;
    float* QO = V + (size_t)N_TOT * DIMM;     // Q fp32; O fp32 in-place

    hipMemsetAsync(d_ws, 0, int_bytes, stream);

    qkv_gemm<<<dim3(12, 257), 256, 0, stream>>>(x, gtok, Wqkv, bqkv, QO, K, V);
    count_edges<<<(E_CSR + 255) / 256, 256, 0, stream>>>(ei, xei, cursor);
    scan_kernel<<<1, 256, 0, stream>>>(cursor, rowstart);
    fill_edges<<<(E_CSR + 255) / 256, 256, 0, stream>>>(ei, xei, cursor, adj);
    attn_kernel<<<N_NODES / 4, 256, 0, stream>>>(QO, K, V, rowstart, adj);
    out_gemm<<<dim3(4, 256), 256, 0, stream>>>(QO, Wout, bout, (float*)d_out);
}

// Round 8
// 237.103 us; speedup vs baseline: 2.0552x; 1.4986x over previous
//
#include <hip/hip_runtime.h>
#include <hip/hip_bf16.h>
#include <stdint.h>

#define N_NODES   16384
#define DIMM      256
#define HEADS     8
#define HDIM      32
#define NUM_GLOBAL 4
#define N_TOT     (N_NODES + NUM_GLOBAL)   // 16388
#define E_LOCAL   131072
#define E_EXP     65536
#define E_CSR     (E_LOCAL + E_EXP)        // 196608

typedef __hip_bfloat16 bf16;
typedef __attribute__((ext_vector_type(8))) short short8;
typedef __attribute__((ext_vector_type(4))) float f32x4;

__device__ __forceinline__ short f2s(float f) {
    bf16 h = __float2bfloat16(f);
    return __builtin_bit_cast(short, h);
}

// XOR swizzle: 16B chunk c of row r stored at chunk (c ^ (r&7) ^ ((r>>3)&7)).
// All ds accesses stay 16B-aligned (row stride 64 shorts = 128B).
__device__ __forceinline__ int swz(int c, int r) {
    return c ^ (r & 7) ^ ((r >> 3) & 7);
}

// ---------------------------------------------------------------------------
// QKV projection (MFMA): X_full(16388x256 fp32) @ Wqkv(256x768 fp32) + b
// -> Q,K,V fp32. fp32 inputs are cast to bf16 during LDS staging; MFMA
// accumulates fp32. 128x128 tile, 4 waves (2x2), 4x4 frags of 16x16x32.
// ---------------------------------------------------------------------------
__global__ __launch_bounds__(256) void qkv_mfma(
    const float* __restrict__ x, const float* __restrict__ gtok,
    const float* __restrict__ W, const float* __restrict__ bias,
    float* __restrict__ Q, float* __restrict__ K, float* __restrict__ V)
{
    __shared__ short As[128 * 64];   // [m][k] bf16, swizzled 16B chunks
    __shared__ short Bs[128 * 64];   // [n][k] bf16 (B^T), swizzled
    const int t  = threadIdx.x;
    const int m0 = blockIdx.y * 128;
    const int n0 = blockIdx.x * 128;           // 0..640
    const int wid = t >> 6, lane = t & 63;
    const int wr = wid >> 1, wc = wid & 1;     // 2x2 wave grid
    const int lm = lane & 15, lq = lane >> 4;  // frag row/col + quad

    f32x4 acc[4][4] = {};

    for (int k0 = 0; k0 < DIMM; k0 += 64) {
        if (k0) __syncthreads();
        // --- stage A: 128 rows x 64 k; 4 short8 chunks per thread ---
        #pragma unroll
        for (int i = 0; i < 4; ++i) {
            int c8 = t + 256 * i;            // 0..1023
            int r  = c8 >> 3, kc = c8 & 7;
            int row = m0 + r;
            float4 v0 = make_float4(0.f, 0.f, 0.f, 0.f), v1 = v0;
            if (row < N_NODES) {
                const float* p = x + (size_t)row * DIMM + k0 + kc * 8;
                v0 = *(const float4*)p; v1 = *(const float4*)(p + 4);
            } else if (row < N_TOT) {
                const float* p = gtok + (size_t)(row - N_NODES) * DIMM + k0 + kc * 8;
                v0 = *(const float4*)p; v1 = *(const float4*)(p + 4);
            }
            short8 o;
            o[0] = f2s(v0.x); o[1] = f2s(v0.y); o[2] = f2s(v0.z); o[3] = f2s(v0.w);
            o[4] = f2s(v1.x); o[5] = f2s(v1.y); o[6] = f2s(v1.z); o[7] = f2s(v1.w);
            *(short8*)(As + r * 64 + swz(kc, r) * 8) = o;
        }
        // --- stage B^T: 64 k x 128 n, register transpose 8k x 4n ---
        {
            const int nc = t & 31;           // 4-col group
            const int kc = t >> 5;           // 8-row (k) group
            float4 wv[8];
            #pragma unroll
            for (int rr = 0; rr < 8; ++rr)
                wv[rr] = *(const float4*)(W + (size_t)(k0 + kc * 8 + rr) * 768 + n0 + nc * 4);
            #pragma unroll
            for (int j = 0; j < 4; ++j) {
                int n = nc * 4 + j;
                short8 o;
                o[0] = f2s(j == 0 ? wv[0].x : j == 1 ? wv[0].y : j == 2 ? wv[0].z : wv[0].w);
                o[1] = f2s(j == 0 ? wv[1].x : j == 1 ? wv[1].y : j == 2 ? wv[1].z : wv[1].w);
                o[2] = f2s(j == 0 ? wv[2].x : j == 1 ? wv[2].y : j == 2 ? wv[2].z : wv[2].w);
                o[3] = f2s(j == 0 ? wv[3].x : j == 1 ? wv[3].y : j == 2 ? wv[3].z : wv[3].w);
                o[4] = f2s(j == 0 ? wv[4].x : j == 1 ? wv[4].y : j == 2 ? wv[4].z : wv[4].w);
                o[5] = f2s(j == 0 ? wv[5].x : j == 1 ? wv[5].y : j == 2 ? wv[5].z : wv[5].w);
                o[6] = f2s(j == 0 ? wv[6].x : j == 1 ? wv[6].y : j == 2 ? wv[6].z : wv[6].w);
                o[7] = f2s(j == 0 ? wv[7].x : j == 1 ? wv[7].y : j == 2 ? wv[7].z : wv[7].w);
                *(short8*)(Bs + n * 64 + swz(kc, n) * 8) = o;
            }
        }
        __syncthreads();
        // --- MFMA: 2 k-blocks of 32; quad lq holds k-chunk (kk*4+lq) ---
        #pragma unroll
        for (int kk = 0; kk < 2; ++kk) {
            const int c = kk * 4 + lq;
            short8 af[4], bfq[4];
            #pragma unroll
            for (int mi = 0; mi < 4; ++mi) {
                int r = wr * 64 + mi * 16 + lm;
                af[mi] = *(const short8*)(As + r * 64 + swz(c, r) * 8);
            }
            #pragma unroll
            for (int ni = 0; ni < 4; ++ni) {
                int n = wc * 64 + ni * 16 + lm;
                bfq[ni] = *(const short8*)(Bs + n * 64 + swz(c, n) * 8);
            }
            #pragma unroll
            for (int mi = 0; mi < 4; ++mi)
                #pragma unroll
                for (int ni = 0; ni < 4; ++ni)
                    acc[mi][ni] = __builtin_amdgcn_mfma_f32_16x16x32_bf16(
                        af[mi], bfq[ni], acc[mi][ni], 0, 0, 0);
        }
    }

    // --- epilogue: C col = lm, row = lq*4+rr (verified layout) ---
    const int colbase = n0 + wc * 64;             // 64-aligned -> one of Q/K/V
    const int sel = colbase >> 8;                 // 0=Q 1=K 2=V
    float* __restrict__ dst = (sel == 0) ? Q : (sel == 1) ? K : V;
    #pragma unroll
    for (int ni = 0; ni < 4; ++ni) {
        int col = colbase + ni * 16 + lm;
        float bv = bias[col];
        int cc = col & 255;
        #pragma unroll
        for (int mi = 0; mi < 4; ++mi) {
            int rowb = m0 + wr * 64 + mi * 16 + lq * 4;
            #pragma unroll
            for (int rr = 0; rr < 4; ++rr) {
                int row = rowb + rr;
                if (row < N_TOT)
                    dst[(size_t)row * DIMM + cc] = acc[mi][ni][rr] + bv;
            }
        }
    }
}

// ---------------------------------------------------------------------------
// Output projection (MFMA): O(16384x256 fp32) @ Wout(256x256 fp32) + bout
// -> out fp32. Same structure; M divisible by 128, no bounds checks.
// ---------------------------------------------------------------------------
__global__ __launch_bounds__(256) void out_mfma(
    const float* __restrict__ O, const float* __restrict__ W,
    const float* __restrict__ bias, float* __restrict__ out)
{
    __shared__ short As[128 * 64];
    __shared__ short Bs[128 * 64];
    const int t  = threadIdx.x;
    const int m0 = blockIdx.y * 128;
    const int n0 = blockIdx.x * 128;           // 0 or 128
    const int wid = t >> 6, lane = t & 63;
    const int wr = wid >> 1, wc = wid & 1;
    const int lm = lane & 15, lq = lane >> 4;

    f32x4 acc[4][4] = {};

    for (int k0 = 0; k0 < DIMM; k0 += 64) {
        if (k0) __syncthreads();
        #pragma unroll
        for (int i = 0; i < 4; ++i) {
            int c8 = t + 256 * i;
            int r  = c8 >> 3, kc = c8 & 7;
            const float* p = O + (size_t)(m0 + r) * DIMM + k0 + kc * 8;
            float4 v0 = *(const float4*)p, v1 = *(const float4*)(p + 4);
            short8 o;
            o[0] = f2s(v0.x); o[1] = f2s(v0.y); o[2] = f2s(v0.z); o[3] = f2s(v0.w);
            o[4] = f2s(v1.x); o[5] = f2s(v1.y); o[6] = f2s(v1.z); o[7] = f2s(v1.w);
            *(short8*)(As + r * 64 + swz(kc, r) * 8) = o;
        }
        {
            const int nc = t & 31;
            const int kc = t >> 5;
            float4 wv[8];
            #pragma unroll
            for (int rr = 0; rr < 8; ++rr)
                wv[rr] = *(const float4*)(W + (size_t)(k0 + kc * 8 + rr) * DIMM + n0 + nc * 4);
            #pragma unroll
            for (int j = 0; j < 4; ++j) {
                int n = nc * 4 + j;
                short8 o;
                o[0] = f2s(j == 0 ? wv[0].x : j == 1 ? wv[0].y : j == 2 ? wv[0].z : wv[0].w);
                o[1] = f2s(j == 0 ? wv[1].x : j == 1 ? wv[1].y : j == 2 ? wv[1].z : wv[1].w);
                o[2] = f2s(j == 0 ? wv[2].x : j == 1 ? wv[2].y : j == 2 ? wv[2].z : wv[2].w);
                o[3] = f2s(j == 0 ? wv[3].x : j == 1 ? wv[3].y : j == 2 ? wv[3].z : wv[3].w);
                o[4] = f2s(j == 0 ? wv[4].x : j == 1 ? wv[4].y : j == 2 ? wv[4].z : wv[4].w);
                o[5] = f2s(j == 0 ? wv[5].x : j == 1 ? wv[5].y : j == 2 ? wv[5].z : wv[5].w);
                o[6] = f2s(j == 0 ? wv[6].x : j == 1 ? wv[6].y : j == 2 ? wv[6].z : wv[6].w);
                o[7] = f2s(j == 0 ? wv[7].x : j == 1 ? wv[7].y : j == 2 ? wv[7].z : wv[7].w);
                *(short8*)(Bs + n * 64 + swz(kc, n) * 8) = o;
            }
        }
        __syncthreads();
        #pragma unroll
        for (int kk = 0; kk < 2; ++kk) {
            const int c = kk * 4 + lq;
            short8 af[4], bfq[4];
            #pragma unroll
            for (int mi = 0; mi < 4; ++mi) {
                int r = wr * 64 + mi * 16 + lm;
                af[mi] = *(const short8*)(As + r * 64 + swz(c, r) * 8);
            }
            #pragma unroll
            for (int ni = 0; ni < 4; ++ni) {
                int n = wc * 64 + ni * 16 + lm;
                bfq[ni] = *(const short8*)(Bs + n * 64 + swz(c, n) * 8);
            }
            #pragma unroll
            for (int mi = 0; mi < 4; ++mi)
                #pragma unroll
                for (int ni = 0; ni < 4; ++ni)
                    acc[mi][ni] = __builtin_amdgcn_mfma_f32_16x16x32_bf16(
                        af[mi], bfq[ni], acc[mi][ni], 0, 0, 0);
        }
    }

    #pragma unroll
    for (int ni = 0; ni < 4; ++ni) {
        int col = n0 + wc * 64 + ni * 16 + lm;
        float bv = bias[col];
        #pragma unroll
        for (int mi = 0; mi < 4; ++mi) {
            int rowb = m0 + wr * 64 + mi * 16 + lq * 4;
            #pragma unroll
            for (int rr = 0; rr < 4; ++rr) {
                float val = acc[mi][ni][rr] + bv;
                val = fminf(fmaxf(val, -1e4f), 1e4f);  // tripwire (no-op valid)
                out[(size_t)(rowb + rr) * DIMM + col] = val;
            }
        }
    }
}

// ---------------------------------------------------------------------------
// CSR build (dst-keyed) for local+expander edges. n2g edges skipped (their
// outputs are discarded by the reference's out[:N]).
// ---------------------------------------------------------------------------
__global__ void count_edges(const int* __restrict__ ei, const int* __restrict__ xei,
                            int* __restrict__ cnt)
{
    int e = blockIdx.x * blockDim.x + threadIdx.x;
    if (e < E_LOCAL) {
        atomicAdd(&cnt[ei[E_LOCAL + e]], 1);
    } else if (e < E_CSR) {
        int ee = e - E_LOCAL;
        atomicAdd(&cnt[xei[E_EXP + ee]], 1);
    }
}

__global__ void scan_kernel(int* __restrict__ cnt_cursor, int* __restrict__ rowstart)
{
    __shared__ int part[256];
    const int t = threadIdx.x;
    const int base = t * 64;
    int s = 0;
    for (int i = 0; i < 64; ++i) s += cnt_cursor[base + i];
    part[t] = s;
    __syncthreads();
    for (int off = 1; off < 256; off <<= 1) {
        int v = (t >= off) ? part[t - off] : 0;
        __syncthreads();
        part[t] += v;
        __syncthreads();
    }
    int excl = part[t] - s;
    for (int i = 0; i < 64; ++i) {
        int v = cnt_cursor[base + i];
        rowstart[base + i]   = excl;
        cnt_cursor[base + i] = excl;
        excl += v;
    }
    if (t == 255) rowstart[N_NODES] = excl;
}

__global__ void fill_edges(const int* __restrict__ ei, const int* __restrict__ xei,
                           int* __restrict__ cursor, int* __restrict__ adj)
{
    int e = blockIdx.x * blockDim.x + threadIdx.x;
    int s, d;
    if (e < E_LOCAL)      { s = ei[e];            d = ei[E_LOCAL + e]; }
    else if (e < E_CSR)   { int ee = e - E_LOCAL; s = xei[ee]; d = xei[E_EXP + ee]; }
    else return;
    int pos = atomicAdd(&cursor[d], 1);
    adj[pos] = s;
}

// ---------------------------------------------------------------------------
// Gather attention (fp32): one wave per dst node, as in R7 (passing).
// ---------------------------------------------------------------------------
__global__ __launch_bounds__(256) void attn_kernel(
    float* __restrict__ QO, const float* __restrict__ K,
    const float* __restrict__ V, const int* __restrict__ rowstart,
    const int* __restrict__ adj)
{
    const int wave = (blockIdx.x * blockDim.x + threadIdx.x) >> 6;
    const int lane = threadIdx.x & 63;
    if (wave >= N_NODES) return;
    const int n = wave;
    const float scale = 0.1767766952966369f;  // 32^-0.5

    float4 q = ((const float4*)(QO + (size_t)n * DIMM))[lane];
    q.x *= scale; q.y *= scale; q.z *= scale; q.w *= scale;

    float4 acc = make_float4(0.f, 0.f, 0.f, 0.f);
    float dsum = 0.f;

    const int rs = rowstart[n];
    const int re = rowstart[n + 1];
    const int ne = (re - rs) + 5;            // self + 4 globals + CSR list

    for (int j = 0; j < ne; ++j) {
        int s;
        if (j == 0)       s = n;
        else if (j <= 4)  s = N_NODES + (j - 1);
        else              s = adj[rs + j - 5];
        s = min(max(s, 0), N_TOT - 1);       // tripwire

        float4 k = ((const float4*)(K + (size_t)s * DIMM))[lane];
        float p = q.x * k.x + q.y * k.y + q.z * k.z + q.w * k.w;
        p += __shfl_xor(p, 1);
        p += __shfl_xor(p, 2);
        p += __shfl_xor(p, 4);               // p = head score in all 8 lanes
        p = fminf(p, 80.f);                  // tripwire (scrubs NaN too)
        float w = __expf(p);
        dsum += w;
        float4 v = ((const float4*)(V + (size_t)s * DIMM))[lane];
        acc.x += w * v.x; acc.y += w * v.y; acc.z += w * v.z; acc.w += w * v.w;
    }

    float r = 1.0f / fmaxf(dsum, 1e-30f);    // tripwire
    acc.x = fminf(fmaxf(acc.x * r, -500.f), 500.f);
    acc.y = fminf(fmaxf(acc.y * r, -500.f), 500.f);
    acc.z = fminf(fmaxf(acc.z * r, -500.f), 500.f);
    acc.w = fminf(fmaxf(acc.w * r, -500.f), 500.f);
    ((float4*)(QO + (size_t)n * DIMM))[lane] = acc;
}

// ---------------------------------------------------------------------------
extern "C" void kernel_launch(void* const* d_in, const int* in_sizes, int n_in,
                              void* d_out, int out_size, void* d_ws, size_t ws_size,
                              hipStream_t stream)
{
    const float* x    = (const float*)d_in[0];
    const int*   ei   = (const int*)d_in[1];
    const int*   xei  = (const int*)d_in[2];
    const float* Wqkv = (const float*)d_in[3];
    const float* bqkv = (const float*)d_in[4];
    const float* Wout = (const float*)d_in[5];
    const float* bout = (const float*)d_in[6];
    const float* gtok = (const float*)d_in[7];

    // workspace layout (~51.2 MB; proven fits):
    int* rowstart = (int*)d_ws;               // N_NODES+1
    int* cursor   = rowstart + (N_NODES + 1); // N_NODES
    int* adj      = cursor + N_NODES;         // E_CSR
    const size_t int_bytes = (size_t)(N_NODES + 1 + N_NODES + E_CSR) * sizeof(int);
    uintptr_t fb = ((uintptr_t)(adj + E_CSR) + 15) & ~(uintptr_t)15;
    float* K  = (float*)fb;
    float* V  = K + (size_t)N_TOT * DIMM;
    float* QO = V + (size_t)N_TOT * DIMM;     // Q fp32; O fp32 in-place

    hipMemsetAsync(d_ws, 0, int_bytes, stream);

    qkv_mfma<<<dim3(6, 129), 256, 0, stream>>>(x, gtok, Wqkv, bqkv, QO, K, V);
    count_edges<<<(E_CSR + 255) / 256, 256, 0, stream>>>(ei, xei, cursor);
    scan_kernel<<<1, 256, 0, stream>>>(cursor, rowstart);
    fill_edges<<<(E_CSR + 255) / 256, 256, 0, stream>>>(ei, xei, cursor, adj);
    attn_kernel<<<N_NODES / 4, 256, 0, stream>>>(QO, K, V, rowstart, adj);
    out_mfma<<<dim3(2, 128), 256, 0, stream>>>(QO, Wout, bout, (float*)d_out);
}

// Round 9
// 200.687 us; speedup vs baseline: 2.4282x; 1.1815x over previous
//
#include <hip/hip_runtime.h>
#include <hip/hip_bf16.h>
#include <stdint.h>

#define N_NODES   16384
#define DIMM      256
#define HEADS     8
#define HDIM      32
#define NUM_GLOBAL 4
#define N_TOT     (N_NODES + NUM_GLOBAL)   // 16388
#define E_LOCAL   131072
#define E_EXP     65536
#define E_CSR     (E_LOCAL + E_EXP)        // 196608

typedef __hip_bfloat16 bf16;
typedef __attribute__((ext_vector_type(8))) short short8;
typedef __attribute__((ext_vector_type(4))) float f32x4;

__device__ __forceinline__ short f2s(float f) {
    bf16 h = __float2bfloat16(f);
    return __builtin_bit_cast(short, h);
}
__device__ __forceinline__ float bu2f(unsigned short u) {
    return __bfloat162float(__builtin_bit_cast(bf16, u));
}

// XOR swizzle: 16B chunk c of row r stored at chunk (c ^ (r&7) ^ ((r>>3)&7)).
__device__ __forceinline__ int swz(int c, int r) {
    return c ^ (r & 7) ^ ((r >> 3) & 7);
}

// ---------------------------------------------------------------------------
// QKV projection (MFMA): X_full(16388x256 fp32) @ Wqkv(256x768 fp32) + b.
// Q -> fp32; K,V -> bf16 (halves the attention gather traffic).
// 128x128 tile, 4 waves (2x2), 4x4 frags of v_mfma_f32_16x16x32_bf16.
// ---------------------------------------------------------------------------
__global__ __launch_bounds__(256) void qkv_mfma(
    const float* __restrict__ x, const float* __restrict__ gtok,
    const float* __restrict__ W, const float* __restrict__ bias,
    float* __restrict__ Q, bf16* __restrict__ Kb, bf16* __restrict__ Vb)
{
    __shared__ short As[128 * 64];   // [m][k] bf16, swizzled 16B chunks
    __shared__ short Bs[128 * 64];   // [n][k] bf16 (B^T), swizzled
    const int t  = threadIdx.x;
    const int m0 = blockIdx.y * 128;
    const int n0 = blockIdx.x * 128;           // 0..640
    const int wid = t >> 6, lane = t & 63;
    const int wr = wid >> 1, wc = wid & 1;
    const int lm = lane & 15, lq = lane >> 4;

    f32x4 acc[4][4] = {};

    for (int k0 = 0; k0 < DIMM; k0 += 64) {
        if (k0) __syncthreads();
        // --- stage A: 128 rows x 64 k; 4 short8 chunks per thread ---
        #pragma unroll
        for (int i = 0; i < 4; ++i) {
            int c8 = t + 256 * i;
            int r  = c8 >> 3, kc = c8 & 7;
            int row = m0 + r;
            float4 v0 = make_float4(0.f, 0.f, 0.f, 0.f), v1 = v0;
            if (row < N_NODES) {
                const float* p = x + (size_t)row * DIMM + k0 + kc * 8;
                v0 = *(const float4*)p; v1 = *(const float4*)(p + 4);
            } else if (row < N_TOT) {
                const float* p = gtok + (size_t)(row - N_NODES) * DIMM + k0 + kc * 8;
                v0 = *(const float4*)p; v1 = *(const float4*)(p + 4);
            }
            short8 o;
            o[0] = f2s(v0.x); o[1] = f2s(v0.y); o[2] = f2s(v0.z); o[3] = f2s(v0.w);
            o[4] = f2s(v1.x); o[5] = f2s(v1.y); o[6] = f2s(v1.z); o[7] = f2s(v1.w);
            *(short8*)(As + r * 64 + swz(kc, r) * 8) = o;
        }
        // --- stage B^T: 64 k x 128 n, register transpose 8k x 4n ---
        {
            const int nc = t & 31;
            const int kc = t >> 5;
            float4 wv[8];
            #pragma unroll
            for (int rr = 0; rr < 8; ++rr)
                wv[rr] = *(const float4*)(W + (size_t)(k0 + kc * 8 + rr) * 768 + n0 + nc * 4);
            #pragma unroll
            for (int j = 0; j < 4; ++j) {
                int n = nc * 4 + j;
                short8 o;
                o[0] = f2s(j == 0 ? wv[0].x : j == 1 ? wv[0].y : j == 2 ? wv[0].z : wv[0].w);
                o[1] = f2s(j == 0 ? wv[1].x : j == 1 ? wv[1].y : j == 2 ? wv[1].z : wv[1].w);
                o[2] = f2s(j == 0 ? wv[2].x : j == 1 ? wv[2].y : j == 2 ? wv[2].z : wv[2].w);
                o[3] = f2s(j == 0 ? wv[3].x : j == 1 ? wv[3].y : j == 2 ? wv[3].z : wv[3].w);
                o[4] = f2s(j == 0 ? wv[4].x : j == 1 ? wv[4].y : j == 2 ? wv[4].z : wv[4].w);
                o[5] = f2s(j == 0 ? wv[5].x : j == 1 ? wv[5].y : j == 2 ? wv[5].z : wv[5].w);
                o[6] = f2s(j == 0 ? wv[6].x : j == 1 ? wv[6].y : j == 2 ? wv[6].z : wv[6].w);
                o[7] = f2s(j == 0 ? wv[7].x : j == 1 ? wv[7].y : j == 2 ? wv[7].z : wv[7].w);
                *(short8*)(Bs + n * 64 + swz(kc, n) * 8) = o;
            }
        }
        __syncthreads();
        #pragma unroll
        for (int kk = 0; kk < 2; ++kk) {
            const int c = kk * 4 + lq;
            short8 af[4], bfq[4];
            #pragma unroll
            for (int mi = 0; mi < 4; ++mi) {
                int r = wr * 64 + mi * 16 + lm;
                af[mi] = *(const short8*)(As + r * 64 + swz(c, r) * 8);
            }
            #pragma unroll
            for (int ni = 0; ni < 4; ++ni) {
                int n = wc * 64 + ni * 16 + lm;
                bfq[ni] = *(const short8*)(Bs + n * 64 + swz(c, n) * 8);
            }
            #pragma unroll
            for (int mi = 0; mi < 4; ++mi)
                #pragma unroll
                for (int ni = 0; ni < 4; ++ni)
                    acc[mi][ni] = __builtin_amdgcn_mfma_f32_16x16x32_bf16(
                        af[mi], bfq[ni], acc[mi][ni], 0, 0, 0);
        }
    }

    // --- epilogue: C col = lm, row = lq*4+rr; sel is wave-uniform ---
    const int colbase = n0 + wc * 64;
    const int sel = colbase >> 8;                 // 0=Q 1=K 2=V
    #pragma unroll
    for (int ni = 0; ni < 4; ++ni) {
        int col = colbase + ni * 16 + lm;
        float bv = bias[col];
        int cc = col & 255;
        #pragma unroll
        for (int mi = 0; mi < 4; ++mi) {
            int rowb = m0 + wr * 64 + mi * 16 + lq * 4;
            #pragma unroll
            for (int rr = 0; rr < 4; ++rr) {
                int row = rowb + rr;
                if (row >= N_TOT) continue;
                float val = acc[mi][ni][rr] + bv;
                if (sel == 0)      Q [(size_t)row * DIMM + cc] = val;
                else if (sel == 1) Kb[(size_t)row * DIMM + cc] = __float2bfloat16(val);
                else               Vb[(size_t)row * DIMM + cc] = __float2bfloat16(val);
            }
        }
    }
}

// ---------------------------------------------------------------------------
// Output projection (MFMA): O(16384x256 bf16) @ Wout(256x256 fp32->bf16)
// + bout -> out fp32. A-staging is a direct short8 copy (no conversion).
// ---------------------------------------------------------------------------
__global__ __launch_bounds__(256) void out_mfma(
    const bf16* __restrict__ O, const float* __restrict__ W,
    const float* __restrict__ bias, float* __restrict__ out)
{
    __shared__ short As[128 * 64];
    __shared__ short Bs[128 * 64];
    const int t  = threadIdx.x;
    const int m0 = blockIdx.y * 128;
    const int n0 = blockIdx.x * 128;           // 0 or 128
    const int wid = t >> 6, lane = t & 63;
    const int wr = wid >> 1, wc = wid & 1;
    const int lm = lane & 15, lq = lane >> 4;

    f32x4 acc[4][4] = {};

    for (int k0 = 0; k0 < DIMM; k0 += 64) {
        if (k0) __syncthreads();
        #pragma unroll
        for (int i = 0; i < 4; ++i) {
            int c8 = t + 256 * i;
            int r  = c8 >> 3, kc = c8 & 7;
            short8 v = *(const short8*)((const short*)O + (size_t)(m0 + r) * DIMM + k0 + kc * 8);
            *(short8*)(As + r * 64 + swz(kc, r) * 8) = v;
        }
        {
            const int nc = t & 31;
            const int kc = t >> 5;
            float4 wv[8];
            #pragma unroll
            for (int rr = 0; rr < 8; ++rr)
                wv[rr] = *(const float4*)(W + (size_t)(k0 + kc * 8 + rr) * DIMM + n0 + nc * 4);
            #pragma unroll
            for (int j = 0; j < 4; ++j) {
                int n = nc * 4 + j;
                short8 o;
                o[0] = f2s(j == 0 ? wv[0].x : j == 1 ? wv[0].y : j == 2 ? wv[0].z : wv[0].w);
                o[1] = f2s(j == 0 ? wv[1].x : j == 1 ? wv[1].y : j == 2 ? wv[1].z : wv[1].w);
                o[2] = f2s(j == 0 ? wv[2].x : j == 1 ? wv[2].y : j == 2 ? wv[2].z : wv[2].w);
                o[3] = f2s(j == 0 ? wv[3].x : j == 1 ? wv[3].y : j == 2 ? wv[3].z : wv[3].w);
                o[4] = f2s(j == 0 ? wv[4].x : j == 1 ? wv[4].y : j == 2 ? wv[4].z : wv[4].w);
                o[5] = f2s(j == 0 ? wv[5].x : j == 1 ? wv[5].y : j == 2 ? wv[5].z : wv[5].w);
                o[6] = f2s(j == 0 ? wv[6].x : j == 1 ? wv[6].y : j == 2 ? wv[6].z : wv[6].w);
                o[7] = f2s(j == 0 ? wv[7].x : j == 1 ? wv[7].y : j == 2 ? wv[7].z : wv[7].w);
                *(short8*)(Bs + n * 64 + swz(kc, n) * 8) = o;
            }
        }
        __syncthreads();
        #pragma unroll
        for (int kk = 0; kk < 2; ++kk) {
            const int c = kk * 4 + lq;
            short8 af[4], bfq[4];
            #pragma unroll
            for (int mi = 0; mi < 4; ++mi) {
                int r = wr * 64 + mi * 16 + lm;
                af[mi] = *(const short8*)(As + r * 64 + swz(c, r) * 8);
            }
            #pragma unroll
            for (int ni = 0; ni < 4; ++ni) {
                int n = wc * 64 + ni * 16 + lm;
                bfq[ni] = *(const short8*)(Bs + n * 64 + swz(c, n) * 8);
            }
            #pragma unroll
            for (int mi = 0; mi < 4; ++mi)
                #pragma unroll
                for (int ni = 0; ni < 4; ++ni)
                    acc[mi][ni] = __builtin_amdgcn_mfma_f32_16x16x32_bf16(
                        af[mi], bfq[ni], acc[mi][ni], 0, 0, 0);
        }
    }

    #pragma unroll
    for (int ni = 0; ni < 4; ++ni) {
        int col = n0 + wc * 64 + ni * 16 + lm;
        float bv = bias[col];
        #pragma unroll
        for (int mi = 0; mi < 4; ++mi) {
            int rowb = m0 + wr * 64 + mi * 16 + lq * 4;
            #pragma unroll
            for (int rr = 0; rr < 4; ++rr) {
                float val = acc[mi][ni][rr] + bv;
                val = fminf(fmaxf(val, -1e4f), 1e4f);  // tripwire (no-op valid)
                out[(size_t)(rowb + rr) * DIMM + col] = val;
            }
        }
    }
}

// ---------------------------------------------------------------------------
// CSR build (dst-keyed) for local+expander edges. n2g edges skipped (their
// outputs are discarded by the reference's out[:N]).
// ---------------------------------------------------------------------------
__global__ void count_edges(const int* __restrict__ ei, const int* __restrict__ xei,
                            int* __restrict__ cnt)
{
    int e = blockIdx.x * blockDim.x + threadIdx.x;
    if (e < E_LOCAL) {
        atomicAdd(&cnt[ei[E_LOCAL + e]], 1);
    } else if (e < E_CSR) {
        int ee = e - E_LOCAL;
        atomicAdd(&cnt[xei[E_EXP + ee]], 1);
    }
}

__global__ void scan_kernel(int* __restrict__ cnt_cursor, int* __restrict__ rowstart)
{
    __shared__ int part[256];
    const int t = threadIdx.x;
    const int base = t * 64;
    int s = 0;
    for (int i = 0; i < 64; ++i) s += cnt_cursor[base + i];
    part[t] = s;
    __syncthreads();
    for (int off = 1; off < 256; off <<= 1) {
        int v = (t >= off) ? part[t - off] : 0;
        __syncthreads();
        part[t] += v;
        __syncthreads();
    }
    int excl = part[t] - s;
    for (int i = 0; i < 64; ++i) {
        int v = cnt_cursor[base + i];
        rowstart[base + i]   = excl;
        cnt_cursor[base + i] = excl;
        excl += v;
    }
    if (t == 255) rowstart[N_NODES] = excl;
}

__global__ void fill_edges(const int* __restrict__ ei, const int* __restrict__ xei,
                           int* __restrict__ cursor, int* __restrict__ adj)
{
    int e = blockIdx.x * blockDim.x + threadIdx.x;
    int s, d;
    if (e < E_LOCAL)      { s = ei[e];            d = ei[E_LOCAL + e]; }
    else if (e < E_CSR)   { int ee = e - E_LOCAL; s = xei[ee]; d = xei[E_EXP + ee]; }
    else return;
    int pos = atomicAdd(&cursor[d], 1);
    adj[pos] = s;
}

// ---------------------------------------------------------------------------
// Gather attention: one wave per dst node; bf16 K/V (half the bytes of R8);
// edges processed in PAIRS so both rows' loads are in flight before either
// reduction (the loop was latency-bound at VALUBusy 14%). Virtual edge index
// domain [rs-5, re): -5=self, -4..-1=globals, >=0 = adj[i].
// O written bf16 to its own slot in Ob. Tripwires are no-ops on valid data.
// ---------------------------------------------------------------------------
__global__ __launch_bounds__(256) void attn_kernel(
    const float* __restrict__ Q, const bf16* __restrict__ Kb,
    const bf16* __restrict__ Vb, const int* __restrict__ rowstart,
    const int* __restrict__ adj, bf16* __restrict__ Ob)
{
    const int wave = (blockIdx.x * blockDim.x + threadIdx.x) >> 6;
    const int lane = threadIdx.x & 63;
    if (wave >= N_NODES) return;
    const int n = wave;
    const float scale = 0.1767766952966369f;  // 32^-0.5

    const ushort4* K4 = (const ushort4*)Kb;
    const ushort4* V4 = (const ushort4*)Vb;

    float4 q = ((const float4*)(Q + (size_t)n * DIMM))[lane];
    q.x *= scale; q.y *= scale; q.z *= scale; q.w *= scale;

    float4 acc = make_float4(0.f, 0.f, 0.f, 0.f);
    float dsum = 0.f;

    const int rs = rowstart[n];
    const int re = rowstart[n + 1];

    for (int i = rs - 5; i < re; i += 2) {
        // src for slot i
        int d0 = i - rs;
        int s0 = (d0 < 0) ? ((d0 == -5) ? n : (N_NODES + d0 + 4)) : adj[i];
        s0 = min(max(s0, 0), N_TOT - 1);
        bool two = (i + 1 < re);
        int d1 = i + 1 - rs;
        int s1 = two ? ((d1 < 0) ? ((d1 == -5) ? n : (N_NODES + d1 + 4)) : adj[i + 1]) : s0;
        s1 = min(max(s1, 0), N_TOT - 1);

        ushort4 k0 = K4[(size_t)s0 * 64 + lane];
        ushort4 k1 = K4[(size_t)s1 * 64 + lane];
        ushort4 v0 = V4[(size_t)s0 * 64 + lane];
        ushort4 v1 = V4[(size_t)s1 * 64 + lane];

        float p0 = q.x * bu2f(k0.x) + q.y * bu2f(k0.y) + q.z * bu2f(k0.z) + q.w * bu2f(k0.w);
        float p1 = q.x * bu2f(k1.x) + q.y * bu2f(k1.y) + q.z * bu2f(k1.z) + q.w * bu2f(k1.w);
        p0 += __shfl_xor(p0, 1);  p1 += __shfl_xor(p1, 1);
        p0 += __shfl_xor(p0, 2);  p1 += __shfl_xor(p1, 2);
        p0 += __shfl_xor(p0, 4);  p1 += __shfl_xor(p1, 4);
        float w0 = __expf(fminf(p0, 80.f));
        float w1 = two ? __expf(fminf(p1, 80.f)) : 0.f;
        dsum += w0 + w1;
        acc.x += w0 * bu2f(v0.x) + w1 * bu2f(v1.x);
        acc.y += w0 * bu2f(v0.y) + w1 * bu2f(v1.y);
        acc.z += w0 * bu2f(v0.z) + w1 * bu2f(v1.z);
        acc.w += w0 * bu2f(v0.w) + w1 * bu2f(v1.w);
    }

    float r = 1.0f / fmaxf(dsum, 1e-30f);    // tripwire
    ushort4 o;
    o.x = (unsigned short)__builtin_bit_cast(short, __float2bfloat16(fminf(fmaxf(acc.x * r, -500.f), 500.f)));
    o.y = (unsigned short)__builtin_bit_cast(short, __float2bfloat16(fminf(fmaxf(acc.y * r, -500.f), 500.f)));
    o.z = (unsigned short)__builtin_bit_cast(short, __float2bfloat16(fminf(fmaxf(acc.z * r, -500.f), 500.f)));
    o.w = (unsigned short)__builtin_bit_cast(short, __float2bfloat16(fminf(fmaxf(acc.w * r, -500.f), 500.f)));
    ((ushort4*)Ob)[(size_t)n * 64 + lane] = o;
}

// ---------------------------------------------------------------------------
extern "C" void kernel_launch(void* const* d_in, const int* in_sizes, int n_in,
                              void* d_out, int out_size, void* d_ws, size_t ws_size,
                              hipStream_t stream)
{
    const float* x    = (const float*)d_in[0];
    const int*   ei   = (const int*)d_in[1];
    const int*   xei  = (const int*)d_in[2];
    const float* Wqkv = (const float*)d_in[3];
    const float* bqkv = (const float*)d_in[4];
    const float* Wout = (const float*)d_in[5];
    const float* bout = (const float*)d_in[6];
    const float* gtok = (const float*)d_in[7];

    // workspace layout (~43.3 MB; ws >= 51.3 MB proven):
    int* rowstart = (int*)d_ws;               // N_NODES+1
    int* cursor   = rowstart + (N_NODES + 1); // N_NODES
    int* adj      = cursor + N_NODES;         // E_CSR
    const size_t int_bytes = (size_t)(N_NODES + 1 + N_NODES + E_CSR) * sizeof(int);
    uintptr_t fb = ((uintptr_t)(adj + E_CSR) + 15) & ~(uintptr_t)15;
    float* Q  = (float*)fb;                        // fp32, N_TOT*256
    bf16*  Kb = (bf16*)(Q + (size_t)N_TOT * DIMM); // bf16, N_TOT*256
    bf16*  Vb = Kb + (size_t)N_TOT * DIMM;         // bf16, N_TOT*256
    bf16*  Ob = Vb + (size_t)N_TOT * DIMM;         // bf16, N_NODES*256

    hipMemsetAsync(d_ws, 0, int_bytes, stream);

    qkv_mfma<<<dim3(6, 129), 256, 0, stream>>>(x, gtok, Wqkv, bqkv, Q, Kb, Vb);
    count_edges<<<(E_CSR + 255) / 256, 256, 0, stream>>>(ei, xei, cursor);
    scan_kernel<<<1, 256, 0, stream>>>(cursor, rowstart);
    fill_edges<<<(E_CSR + 255) / 256, 256, 0, stream>>>(ei, xei, cursor, adj);
    attn_kernel<<<N_NODES / 4, 256, 0, stream>>>(Q, Kb, Vb, rowstart, adj, Ob);
    out_mfma<<<dim3(2, 128), 256, 0, stream>>>(Ob, Wout, bout, (float*)d_out);
}